// Round 11
// baseline (252.343 us; speedup 1.0000x reference)
//
#include <hip/hip_runtime.h>
#include <hip/hip_bf16.h>
#include <math.h>

// Problem constants
#define B_   4
#define N_   2048
#define DIM_ 1024
#define H_   16
#define DH_  64
#define E3_  3072   // 3*H*DH

typedef __attribute__((ext_vector_type(8)))  short s8v;   // 8 bf16 (4 VGPRs)
typedef __attribute__((ext_vector_type(4)))  float f4v;   // 16x16 MFMA accumulator
typedef __attribute__((ext_vector_type(16))) float f16v;  // 32x32 MFMA accumulator

// fast fp32->bf16: round-half-up (adds 0.5 ulp then truncate). 2 VALU ops.
__device__ __forceinline__ unsigned short f2bf_fast(float f) {
    return (unsigned short)((__builtin_bit_cast(unsigned int, f) + 0x8000u) >> 16);
}
// pack two fp32 -> two bf16 in one u32 via v_perm_b32 (3 VALU ops total)
__device__ __forceinline__ unsigned int pkbf(float a, float b) {
    unsigned int ua = __builtin_bit_cast(unsigned int, a) + 0x8000u;
    unsigned int ub = __builtin_bit_cast(unsigned int, b) + 0x8000u;
    return __builtin_amdgcn_perm(ub, ua, 0x07060302);
}
// single-instruction pack: dst.lo = bf16(a), dst.hi = bf16(b)  (RNE)
__device__ __forceinline__ unsigned int cvtpk(float a, float b) {
    unsigned int r;
    asm("v_cvt_pk_bf16_f32 %0, %1, %2" : "=v"(r) : "v"(a), "v"(b));
    return r;
}
// v_permlane32_swap_b32: after execution
//   a' = [a(lanes 0:31) | b(lanes 0:31)],  b' = [a(lanes 32:63) | b(lanes 32:63)]
__device__ __forceinline__ uint2 pl32(unsigned int a, unsigned int b) {
    asm volatile("v_permlane32_swap_b32 %0, %1" : "+v"(a), "+v"(b));
    return make_uint2(a, b);
}

// async global->LDS, 16 B per lane; LDS dest = wave-uniform base + lane*16
__device__ __forceinline__ void gload_lds16(const void* g, void* l) {
    __builtin_amdgcn_global_load_lds(
        (const __attribute__((address_space(1))) unsigned int*)(uintptr_t)g,
        (__attribute__((address_space(3))) unsigned int*)(uintptr_t)l,
        16, 0, 0);
}

// ---------------------------------------------------------------------------
// fused fp32 -> bf16 convert for all three inputs (1 dispatch)
// ---------------------------------------------------------------------------
__global__ __launch_bounds__(256) void cvt_all(
    const float* __restrict__ x,  const float* __restrict__ wq,
    const float* __restrict__ wo,
    unsigned short* __restrict__ xb, unsigned short* __restrict__ wqb,
    unsigned short* __restrict__ wob)
{
    const int bid = blockIdx.x;
    const float* in; unsigned short* out; int rb;
    if (bid < 8192)       { in = x;  out = xb;  rb = bid; }
    else if (bid < 11264) { in = wq; out = wqb; rb = bid - 8192; }
    else                  { in = wo; out = wob; rb = bid - 11264; }
    const int i = (rb * 256 + threadIdx.x) * 4;
    float4 v = *(const float4*)(in + i);
    uint2 pk;
    pk.x = pkbf(v.x, v.y);
    pk.y = pkbf(v.z, v.w);
    *(uint2*)(out + i) = pk;
}

// ---------------------------------------------------------------------------
// QKV projection GEMM v5: 3-SLOT RING, 2-ahead counted vmcnt.
// Round-10 NaN root cause: the 4-slot ring was sized in bytes-think
// (Ls[4][14336]) while tiles are 28672 ELEMENTS -> slot overflow; and a
// correctly-sized 4-slot ring (4x56KB=224KB) cannot fit LDS. Restated with
// capacity arithmetic: 2-ahead needs only 3 live tiles; a 3-slot ring is
// WAR-safe with ONE barrier/iter (slot (t+2)%3 last read at iter t-1, whose
// end barrier precedes this iter's issue; reads are MFMA-consumed pre-barrier).
// Tile re-sized to fit: BM256 x BN128 x BK64 -> (256+128)*64 = 24576 el =
// 48KB/slot, 3 slots = 144KB <= 160KB. 512 thr = 8 waves (2M x 4N), wave
// tile 128x32 = 8x2 MFMAs x 2 ksteps = 32 MFMA vs 20 b128 per iter.
// 6 loads/wave/tile -> vmcnt(6) at iter end certifies tile t+1 with a
// TWO-compute-phase latency window (~1000cy >= HBM ~900cy); the old 2-buf
// scheme's window was one phase (~500cy) -> ~400cy stall/iter (25-35%).
// grid (24,32) = 768 blocks (%8==0, 3 rounds). Both-sides swizzle as before.
// Q-third pre-scaled by 0.125*log2(e); V-third redirected to vT[b,h,d,n].
// ---------------------------------------------------------------------------
__global__ __launch_bounds__(512, 1) void gemm_qkv(
    const unsigned short* __restrict__ A,    // x_bf [8192][1024]
    const unsigned short* __restrict__ Bw,   // wqkv_bf [3072][1024]
    unsigned short* __restrict__ Cb,         // qkv bf16 [8192][3072]
    unsigned short* __restrict__ Vt)         // [B*H][64][2048]
{
    __shared__ unsigned short Ls[3][24576];  // 3-slot ring, 48KB each = 144KB

    const int tid  = threadIdx.x;
    const int w    = tid >> 6;          // 0..7
    const int lane = tid & 63;
    const int quad = lane >> 4;
    const int l15  = lane & 15;
    const int wm   = w & 1;             // M half (128 rows)
    const int wn   = w >> 1;            // N quarter (32 cols)

    // XCD-chunked swizzle: 768 blocks -> 96 per XCD (4 m-panels x 24 n-tiles)
    const int lin = blockIdx.y * 24 + blockIdx.x;
    const int swz = (lin & 7) * 96 + (lin >> 3);
    const int m0  = (swz / 24) * 256;
    const int n0  = (swz % 24) * 128;

    // staging: 48 units of 1KB (8 rows x 64 el); wave w stages units
    // w*6..w*6+5. Lane: row = unit*8 + (lane>>3), source chunk pre-swizzled.
    const int r8  = lane >> 3;              // 0..7
    const int chk = (lane & 7) ^ r8;        // pre-swizzled source chunk

    f4v acc[8][2];
    #pragma unroll
    for (int i = 0; i < 8; i++)
        #pragma unroll
        for (int j = 0; j < 2; j++) acc[i][j] = (f4v){0.f, 0.f, 0.f, 0.f};

    #define QKV_STAGE(slot, kk)                                                 \
        _Pragma("unroll")                                                       \
        for (int j = 0; j < 6; j++) {                                           \
            const int u = w * 6 + j;                                            \
            const unsigned short* src = (u < 32)                                \
                ? A  + (size_t)(m0 + u * 8 + r8) * 1024 + (kk) + chk * 8        \
                : Bw + (size_t)(n0 + (u - 32) * 8 + r8) * 1024 + (kk) + chk * 8;\
            gload_lds16(src, &Ls[slot][u * 512]);                               \
        }

    // ---- prologue: stage tiles 0,1; certify tile 0 (6 newest outstanding) --
    QKV_STAGE(0, 0);
    QKV_STAGE(1, 64);
    asm volatile("s_waitcnt vmcnt(6)" ::: "memory");
    __builtin_amdgcn_s_barrier();
    __builtin_amdgcn_sched_barrier(0);

    for (int t = 0; t < 16; t++) {
        const int cur = t % 3;

        // ---- issue tile t+2 into ring slot (2-ahead; WAR: slot last read
        //      at iter t-1, separated by that iter's end barrier) ----
        if (t + 2 < 16) { QKV_STAGE((t + 2) % 3, (t + 2) * 64); }

        // ---- compute on current slot: 2 k-steps x (8x2) MFMAs ----
        #pragma unroll
        for (int s = 0; s < 2; s++) {
            s8v af[8], bf[2];
            #pragma unroll
            for (int ms = 0; ms < 8; ms++) {
                const int row = wm * 128 + ms * 16 + l15;
                af[ms] = *(const s8v*)&Ls[cur][row * 64 + (((s * 4 + quad) ^ (l15 & 7)) * 8)];
            }
            #pragma unroll
            for (int ns = 0; ns < 2; ns++) {
                const int row = 256 + wn * 32 + ns * 16 + l15;
                bf[ns] = *(const s8v*)&Ls[cur][row * 64 + (((s * 4 + quad) ^ (l15 & 7)) * 8)];
            }
            __builtin_amdgcn_s_setprio(1);
            #pragma unroll
            for (int ms = 0; ms < 8; ms++)
                #pragma unroll
                for (int ns = 0; ns < 2; ns++)
                    acc[ms][ns] = __builtin_amdgcn_mfma_f32_16x16x32_bf16(
                        af[ms], bf[ns], acc[ms][ns], 0, 0, 0);
            __builtin_amdgcn_s_setprio(0);
        }

        // ---- certify tile t+1 (its 6 loads older than the 6 just issued) --
        if (t + 2 < 16)      { asm volatile("s_waitcnt vmcnt(6)" ::: "memory"); }
        else if (t + 1 < 16) { asm volatile("s_waitcnt vmcnt(0)" ::: "memory"); }
        __builtin_amdgcn_s_barrier();
        __builtin_amdgcn_sched_barrier(0);
    }
    #undef QKV_STAGE

    // ---- epilogue: C/D layout col = l15, row = quad*4 + r ----
    #pragma unroll
    for (int ns = 0; ns < 2; ns++) {
        const int colb = n0 + wn * 32 + ns * 16;   // wave-uniform, 16-aligned
        if (colb < 2048) {
            const float mul = (colb < 1024) ? 0.18033688011112042f : 1.0f;
            #pragma unroll
            for (int ms = 0; ms < 8; ms++)
                #pragma unroll
                for (int r = 0; r < 4; r++) {
                    const int row = m0 + wm * 128 + ms * 16 + quad * 4 + r;
                    Cb[(size_t)row * E3_ + colb + l15] = f2bf_fast(acc[ms][ns][r] * mul);
                }
        } else {
            const int e = colb + l15 - 2048;
            const int hh = e >> 6, d = e & 63;       // wave-uniform head
            #pragma unroll
            for (int ms = 0; ms < 8; ms++) {
                const int row = m0 + wm * 128 + ms * 16 + quad * 4;  // 4-aligned
                const int bb = row >> 11, nn = row & 2047;
                uint2 pk;
                pk.x = pkbf(acc[ms][ns][0], acc[ms][ns][1]);
                pk.y = pkbf(acc[ms][ns][2], acc[ms][ns][3]);
                *(uint2*)&Vt[(((size_t)bb * 16 + hh) * 64 + d) * 2048 + nn] = pk;
            }
        }
    }
}

// ---------------------------------------------------------------------------
// out projection GEMM v4: same 3-slot/2-ahead template. BM128 x BN256 x BK64
// -> (128+256)*64 = 24576 el = 48KB/slot, 144KB total. 512 thr = 8 waves
// (2M x 4N), wave tile 64x64 = 4x4 MFMAs x 2 ksteps. grid (4,64) = 256
// blocks = exactly 1 round; 8 waves/CU (same as the old 2x4-wave config).
// 6 loads/wave/tile -> vmcnt(6).
// ---------------------------------------------------------------------------
__global__ __launch_bounds__(512, 1) void gemm_out(
    const unsigned short* __restrict__ A,    // ao_bf [8192][1024]
    const unsigned short* __restrict__ Bw,   // wout_bf [1024][1024]
    const float* __restrict__ bias,
    float* __restrict__ Cf)                  // out fp32 [8192][1024]
{
    __shared__ unsigned short Ls[3][24576];  // 3-slot ring, 48KB each = 144KB

    const int tid  = threadIdx.x;
    const int w    = tid >> 6;          // 0..7
    const int lane = tid & 63;
    const int quad = lane >> 4;
    const int l15  = lane & 15;
    const int wm   = w & 1;             // M half (64 rows)
    const int wn   = w >> 1;            // N quarter (64 cols)

    // XCD-chunked swizzle: 256 blocks -> 32 per XCD
    const int lin = blockIdx.y * 4 + blockIdx.x;
    const int swz = (lin & 7) * 32 + (lin >> 3);
    const int m0  = (swz >> 2) * 128;
    const int n0  = (swz & 3) * 256;

    const int r8  = lane >> 3;              // 0..7
    const int chk = (lane & 7) ^ r8;        // pre-swizzled source chunk

    f4v acc[4][4];
    #pragma unroll
    for (int i = 0; i < 4; i++)
        #pragma unroll
        for (int j = 0; j < 4; j++) acc[i][j] = (f4v){0.f, 0.f, 0.f, 0.f};

    #define OUT_STAGE(slot, kk)                                                 \
        _Pragma("unroll")                                                       \
        for (int j = 0; j < 6; j++) {                                           \
            const int u = w * 6 + j;                                            \
            const unsigned short* src = (u < 16)                                \
                ? A  + (size_t)(m0 + u * 8 + r8) * 1024 + (kk) + chk * 8        \
                : Bw + (size_t)(n0 + (u - 16) * 8 + r8) * 1024 + (kk) + chk * 8;\
            gload_lds16(src, &Ls[slot][u * 512]);                               \
        }

    // ---- prologue: stage tiles 0,1; certify tile 0 ----
    OUT_STAGE(0, 0);
    OUT_STAGE(1, 64);
    asm volatile("s_waitcnt vmcnt(6)" ::: "memory");
    __builtin_amdgcn_s_barrier();
    __builtin_amdgcn_sched_barrier(0);

    for (int t = 0; t < 16; t++) {
        const int cur = t % 3;

        if (t + 2 < 16) { OUT_STAGE((t + 2) % 3, (t + 2) * 64); }

        #pragma unroll
        for (int s = 0; s < 2; s++) {
            s8v af[4], bf[4];
            #pragma unroll
            for (int ms = 0; ms < 4; ms++) {
                const int row = wm * 64 + ms * 16 + l15;
                af[ms] = *(const s8v*)&Ls[cur][row * 64 + (((s * 4 + quad) ^ (l15 & 7)) * 8)];
            }
            #pragma unroll
            for (int ns = 0; ns < 4; ns++) {
                const int row = 128 + wn * 64 + ns * 16 + l15;
                bf[ns] = *(const s8v*)&Ls[cur][row * 64 + (((s * 4 + quad) ^ (l15 & 7)) * 8)];
            }
            __builtin_amdgcn_s_setprio(1);
            #pragma unroll
            for (int ms = 0; ms < 4; ms++)
                #pragma unroll
                for (int ns = 0; ns < 4; ns++)
                    acc[ms][ns] = __builtin_amdgcn_mfma_f32_16x16x32_bf16(
                        af[ms], bf[ns], acc[ms][ns], 0, 0, 0);
            __builtin_amdgcn_s_setprio(0);
        }

        if (t + 2 < 16)      { asm volatile("s_waitcnt vmcnt(6)" ::: "memory"); }
        else if (t + 1 < 16) { asm volatile("s_waitcnt vmcnt(0)" ::: "memory"); }
        __builtin_amdgcn_s_barrier();
        __builtin_amdgcn_sched_barrier(0);
    }
    #undef OUT_STAGE

    // ---- epilogue: fp32 + bias ----
    #pragma unroll
    for (int ns = 0; ns < 4; ns++) {
        const float bz = bias[n0 + wn * 64 + ns * 16 + l15];
        #pragma unroll
        for (int ms = 0; ms < 4; ms++)
            #pragma unroll
            for (int r = 0; r < 4; r++) {
                const int row = m0 + wm * 64 + ms * 16 + quad * 4 + r;
                Cf[(size_t)row * 1024 + n0 + wn * 64 + ns * 16 + l15] =
                    acc[ms][ns][r] + bz;
            }
    }
}

// ---------------------------------------------------------------------------
// MFMA flash attention v7 (verbatim — 80us, CONTROL)
// ---------------------------------------------------------------------------
__global__ __launch_bounds__(512, 4) void attn_mfma(
    const unsigned short* __restrict__ qkv,
    const unsigned short* __restrict__ vT,
    unsigned short* __restrict__ ao)
{
    __shared__ __align__(16) unsigned short Ks[2][64][64];   // [buf][key][d] swz
    __shared__ __align__(16) unsigned short Vs[2][64][64];   // [buf][d][key] swz

    const int tid  = threadIdx.x;
    const int w    = tid >> 6;          // 0..7
    const int lane = tid & 63;
    const int l31  = lane & 31;
    const int hi5  = lane >> 5;         // 0/1
    const int h8   = hi5 * 8;

    const int lin = blockIdx.y * 8 + blockIdx.x;
    const int swz = (lin & 7) * 64 + (lin >> 3);
    const int bx  = swz & 7;
    const int bh  = swz >> 3;
    const int b   = bh >> 4;
    const int h   = bh & 15;
    const int q0  = bx * 256;           // 256 q-rows per block
    const int qb  = q0 + w * 32;        // 32 q-rows per wave

    const unsigned short* qp  = qkv + (size_t)b * N_ * E3_ + (size_t)h * DH_;
    const unsigned short* kp  = qp + 1024;
    const unsigned short* vtp = vT + (size_t)bh * 64 * 2048;

    const int drow = lane >> 3;             // 0..7 within slice
    const int dchk = (lane & 7) ^ drow;     // pre-swizzled source chunk
    const int grow = w * 8 + drow;          // row 0..63 (grow&7 == drow)

    s8v bq[4];
    {
        const unsigned short* qrow = qp + (size_t)(qb + l31) * E3_;
        #pragma unroll
        for (int ks = 0; ks < 4; ks++)
            bq[ks] = *(const s8v*)(qrow + ks * 16 + h8);
    }

    s8v ones;
    #pragma unroll
    for (int i = 0; i < 8; i++) ones[i] = (short)0x3F80;

    const f16v fzero = {0.f,0.f,0.f,0.f,0.f,0.f,0.f,0.f,
                        0.f,0.f,0.f,0.f,0.f,0.f,0.f,0.f};
    f16v o0 = fzero, o1 = fzero;   // d = 0..31 / 32..63
    f16v lc = fzero;               // row-sums, layout-matched to o

    gload_lds16(kp  + (size_t)grow * E3_  + dchk * 8, &Ks[0][w * 8][0]);
    gload_lds16(vtp + (size_t)grow * 2048 + dchk * 8, &Vs[0][w * 8][0]);
    __syncthreads();   // vmcnt(0) drain + barrier

    for (int kt = 0; kt < N_ / 64; kt++) {
        const int cur = kt & 1;

        if (kt + 1 < N_ / 64) {
            const int kn = (kt + 1) * 64;
            gload_lds16(kp  + (size_t)(kn + grow) * E3_  + dchk * 8,
                        &Ks[cur ^ 1][w * 8][0]);
            gload_lds16(vtp + (size_t)grow * 2048 + kn + dchk * 8,
                        &Vs[cur ^ 1][w * 8][0]);
        }

        #pragma unroll
        for (int ksub = 0; ksub < 2; ksub++) {
            const int krow = ksub * 32 + l31;
            const int ksw  = (l31 & 7) * 8;     // krow&7 == l31&7
            s8v ak[4];
            #pragma unroll
            for (int ks = 0; ks < 4; ks++)
                ak[ks] = *(const s8v*)&Ks[cur][krow][(ks * 16 + h8) ^ ksw];

            f16v st = fzero;
            __builtin_amdgcn_s_setprio(1);
            st = __builtin_amdgcn_mfma_f32_32x32x16_bf16(ak[0], bq[0], st, 0, 0, 0);
            st = __builtin_amdgcn_mfma_f32_32x32x16_bf16(ak[1], bq[1], st, 0, 0, 0);
            st = __builtin_amdgcn_mfma_f32_32x32x16_bf16(ak[2], bq[2], st, 0, 0, 0);
            st = __builtin_amdgcn_mfma_f32_32x32x16_bf16(ak[3], bq[3], st, 0, 0, 0);
            __builtin_amdgcn_s_setprio(0);

            float pe[16];
            #pragma unroll
            for (int i = 0; i < 16; i++)
                pe[i] = __builtin_amdgcn_exp2f(st[i]);

            s8v pa[2];
            {
                union { s8v v; unsigned int u[4]; } f0, f1;
                uint2 r;
                r = pl32(cvtpk(pe[0],  pe[1]),  cvtpk(pe[4],  pe[5]));
                f0.u[0] = r.x; f0.u[2] = r.y;
                r = pl32(cvtpk(pe[2],  pe[3]),  cvtpk(pe[6],  pe[7]));
                f0.u[1] = r.x; f0.u[3] = r.y;
                r = pl32(cvtpk(pe[8],  pe[9]),  cvtpk(pe[12], pe[13]));
                f1.u[0] = r.x; f1.u[2] = r.y;
                r = pl32(cvtpk(pe[10], pe[11]), cvtpk(pe[14], pe[15]));
                f1.u[1] = r.x; f1.u[3] = r.y;
                pa[0] = f0.v;   // keys ksub*32 + 0..15
                pa[1] = f1.v;   // keys ksub*32 + 16..31
            }

            #pragma unroll
            for (int j = 0; j < 2; j++) {
                const int kbase = (ksub * 2 + j) * 16 + h8;
                const int vsw   = (l31 & 7) * 8;
                s8v bv0 = *(const s8v*)&Vs[cur][l31     ][kbase ^ vsw];
                s8v bv1 = *(const s8v*)&Vs[cur][32 + l31][kbase ^ vsw];
                __builtin_amdgcn_s_setprio(1);
                o0 = __builtin_amdgcn_mfma_f32_32x32x16_bf16(pa[j], bv0, o0, 0, 0, 0);
                o1 = __builtin_amdgcn_mfma_f32_32x32x16_bf16(pa[j], bv1, o1, 0, 0, 0);
                lc = __builtin_amdgcn_mfma_f32_32x32x16_bf16(pa[j], ones, lc, 0, 0, 0);
                __builtin_amdgcn_s_setprio(0);
            }
        }

        __syncthreads();
    }

    {
        float inv[16];
        #pragma unroll
        for (int r = 0; r < 16; r++) inv[r] = 1.f / lc[r];
        #pragma unroll
        for (int r = 0; r < 16; r++) {
            const int qrow = qb + (r & 3) + 8 * (r >> 2) + 4 * hi5;
            const size_t base = ((size_t)b * N_ + qrow) * (H_ * DH_) + h * DH_;
            ao[base + l31]      = f2bf_fast(o0[r] * inv[r]);
            ao[base + 32 + l31] = f2bf_fast(o1[r] * inv[r]);
        }
    }
}

// ---------------------------------------------------------------------------
// Launch — 4 dispatches
// ---------------------------------------------------------------------------
extern "C" void kernel_launch(void* const* d_in, const int* in_sizes, int n_in,
                              void* d_out, int out_size, void* d_ws, size_t ws_size,
                              hipStream_t stream) {
    const float* x     = (const float*)d_in[0];   // [B,N,DIM]
    const float* w_qkv = (const float*)d_in[1];   // [3072, 1024]
    const float* w_out = (const float*)d_in[2];   // [1024, 1024]
    const float* b_out = (const float*)d_in[3];   // [1024]
    float* out = (float*)d_out;                   // [B,N,DIM] fp32

    char* ws = (char*)d_ws;
    unsigned short* x_bf    = (unsigned short*)(ws);                        // 16 MB
    unsigned short* wqkv_bf = (unsigned short*)(ws + (((size_t)16) << 20)); //  6 MB
    unsigned short* wout_bf = (unsigned short*)(ws + (((size_t)22) << 20)); //  2 MB
    unsigned short* qkv_bf  = (unsigned short*)(ws + (((size_t)24) << 20)); // 48 MB
    unsigned short* vT      = (unsigned short*)(ws + (((size_t)72) << 20)); // 16 MB
    unsigned short* ao_bf   = (unsigned short*)(ws + (((size_t)88) << 20)); // 16 MB

    const int M = B_ * N_;   // 8192

    // 0) fused input conversions fp32 -> bf16 (1 dispatch)
    cvt_all<<<12288, 256, 0, stream>>>(x, w_qkv, w_out, x_bf, wqkv_bf, wout_bf);

    // 1) QKV projection v5: 256x128x64 tiles, 3-slot ring + counted vmcnt
    {
        dim3 grid(E3_ / 128, M / 256);   // (24, 32) = 768 blocks
        gemm_qkv<<<grid, 512, 0, stream>>>(x_bf, wqkv_bf, qkv_bf, vT);
    }
    // 2) attention v7: unchanged control (80us)
    {
        dim3 grid(N_ / 256, B_ * H_);    // (8, 64) = 512 blocks
        attn_mfma<<<grid, 512, 0, stream>>>(qkv_bf, vT, ao_bf);
    }
    // 3) out projection v4: 128x256x64 tiles, 3-slot ring + counted vmcnt
    {
        dim3 grid(DIM_ / 256, M / 128);  // (4, 64) = 256 blocks
        gemm_out<<<grid, 512, 0, stream>>>(ao_bf, wout_bf, b_out, out);
    }
    (void)in_sizes; (void)n_in; (void)out_size; (void)ws_size;
}